// Round 14
// baseline (140.838 us; speedup 1.0000x reference)
//
#include <hip/hip_runtime.h>
#include <math.h>

#define D      4096
#define NPREV  8191
#define NROWS  8192
#define NWAVE  2048
#define RPW    4

typedef float f4 __attribute__((ext_vector_type(4)));

static __device__ __forceinline__ f4 nt_load4(const float* p) {
    return __builtin_nontemporal_load(reinterpret_cast<const f4*>(p));
}
static __device__ __forceinline__ void nt_store4(f4 v, float* p) {
    __builtin_nontemporal_store(v, reinterpret_cast<f4*>(p));
}
static __device__ __forceinline__ f4 ld4(const float* p) {
    return *reinterpret_cast<const f4*>(p);
}
static __device__ __forceinline__ void st4(f4 v, float* p) {
    *reinterpret_cast<f4*>(p) = v;
}

// ---- K1/K6: out[row] = dot(W[row,:], v) (+resid). 1024 blocks x 256 ---------
template<bool RESIDUAL>
__global__ void k_matvec_rows(const float* __restrict__ W, const float* __restrict__ v,
                              const float* __restrict__ resid, float* __restrict__ out) {
    int row  = blockIdx.x * 4 + (threadIdx.x >> 6);
    int lane = threadIdx.x & 63;
    const float* Wrow = W + (size_t)row * D;
    float acc = 0.f;
    #pragma unroll
    for (int i = 0; i < 16; ++i) {
        int c = lane + i * 64;
        f4 w = nt_load4(Wrow + 4 * c);
        f4 x = ld4(v + 4 * c);
        acc += w.x * x.x + w.y * x.y + w.z * x.z + w.w * x.w;
    }
    #pragma unroll
    for (int off = 32; off; off >>= 1) acc += __shfl_down(acc, off, 64);
    if (lane == 0) out[row] = RESIDUAL ? (acc + resid[row]) : acc;
}

// ---- K2: kq[d] = sum_m q[m] * W_K[m][d]. 256 blocks x 256 -------------------
__global__ void k_kq(const float* __restrict__ W, const float* __restrict__ q,
                     float* __restrict__ kq) {
    __shared__ float s_q[D];            // 16 KB
    __shared__ f4 s_part[64][4];        // 4 KB
    int t = threadIdx.x;
    int b = blockIdx.x;
    for (int i = t; i < D; i += 256) s_q[i] = q[i];
    __syncthreads();
    int c4 = b * 4 + (t & 3);           // f4 column
    int r0 = t >> 2;                    // 0..63
    f4 acc = (f4)0.f;
    #pragma unroll 16
    for (int i = 0; i < 64; ++i) {
        int m = r0 + i * 64;
        acc += s_q[m] * nt_load4(W + (size_t)m * D + 4 * c4);
    }
    s_part[r0][t & 3] = acc;
    __syncthreads();
    if (t < 4) {
        f4 a = (f4)0.f;
        #pragma unroll
        for (int g = 0; g < 64; ++g) a += s_part[g][t];
        st4(a, kq + 4 * (b * 4 + t));
    }
}

// ---- K3: pure grid-stride copy prev(+inp) -> io. 2048 blocks x 256 ----------
// Exactly the float4-copy ubench shape: whole grid sweeps a contiguous 8 MB
// window per iteration. Regular loads (fill L3 with prev for the flash);
// nt stores (io bypasses cache, doesn't evict prev).
#define CPY_THREADS (2048 * 256)
#define CPY_ITERS   ((NROWS * (D / 4)) / CPY_THREADS)   // 16
__global__ __launch_bounds__(256) void k_copy(
        const float* __restrict__ prev, const float* __restrict__ inp,
        float* __restrict__ io) {
    size_t base = (size_t)blockIdx.x * 256 + threadIdx.x;
    #pragma unroll
    for (int i = 0; i < CPY_ITERS; ++i) {
        size_t idx = base + (size_t)i * CPY_THREADS;    // f4 index
        f4 v = (idx < (size_t)NPREV * (D / 4))
                 ? ld4(prev + 4 * idx)
                 : ld4(inp + 4 * (idx - (size_t)NPREV * (D / 4)));
        nt_store4(v, io + 4 * idx);
    }
}

// ---- K4: read-only wave-autonomous flash (proven in R12/R13) ----------------
__global__ __launch_bounds__(256, 2) void k_flash_pure(
        const float* __restrict__ prev, const float* __restrict__ inp,
        const float* __restrict__ kq,
        float* __restrict__ ms, float* __restrict__ ctxpart) {
    const int t = threadIdx.x;
    const int lane = t & 63;
    const int gw = blockIdx.x * 4 + (t >> 6);     // global wave 0..2047

    f4 kqr[16];
    #pragma unroll
    for (int i = 0; i < 16; ++i) kqr[i] = ld4(kq + 4 * (lane + 64 * i));

    float m = -INFINITY, s = 0.f;
    f4 a[16];
    #pragma unroll
    for (int i = 0; i < 16; ++i) a[i] = (f4)0.f;

    for (int k = 0; k < RPW; ++k) {
        int n = gw + NWAVE * k;
        const float* src = (n < NPREV) ? (prev + (size_t)n * D) : inp;
        f4 x[16];
        #pragma unroll
        for (int i = 0; i < 16; ++i) x[i] = ld4(src + 4 * (lane + 64 * i));
        float p = 0.f;
        #pragma unroll
        for (int i = 0; i < 16; ++i)
            p += x[i].x * kqr[i].x + x[i].y * kqr[i].y
               + x[i].z * kqr[i].z + x[i].w * kqr[i].w;
        #pragma unroll
        for (int off = 32; off; off >>= 1) p += __shfl_down(p, off, 64);
        p = __shfl(p, 0, 64);                      // broadcast row logit
        if (p > m) {                               // wave-uniform rescale
            float sc = __expf(m - p);              // first row: exp(-inf)=0
            s *= sc;
            #pragma unroll
            for (int i = 0; i < 16; ++i) a[i] *= sc;
            m = p;
        }
        float e = __expf(p - m);
        s += e;
        #pragma unroll
        for (int i = 0; i < 16; ++i) a[i] += e * x[i];
    }
    float* cp = ctxpart + (size_t)gw * D;
    #pragma unroll
    for (int i = 0; i < 16; ++i) st4(a[i], cp + 4 * (lane + 64 * i));
    if (lane == 0) { ms[2 * gw] = m; ms[2 * gw + 1] = s; }
}

// ---- K5: combine FBT partials -> normalized ctx. 64 blocks x 256 ------------
template<int FBT>
__global__ void k_combine(const float* __restrict__ ms, const float* __restrict__ ctxpart,
                          float* __restrict__ ctx) {
    constexpr int PPT = FBT / 256;      // ms pairs per thread
    constexpr int PPG = FBT / 16;       // partials per group-thread
    __shared__ float s_w[FBT];
    __shared__ float s_red[8];
    __shared__ f4 s_acc[16][16];
    int t = threadIdx.x;                // 256
    int lane = t & 63, wid = t >> 6;
    float mloc[PPT];
    float mx = -INFINITY;
    #pragma unroll
    for (int k = 0; k < PPT; ++k) { mloc[k] = ms[2 * (t + 256 * k)]; mx = fmaxf(mx, mloc[k]); }
    #pragma unroll
    for (int off = 32; off; off >>= 1) mx = fmaxf(mx, __shfl_down(mx, off, 64));
    if (lane == 0) s_red[wid] = mx;
    __syncthreads();
    float M = fmaxf(fmaxf(s_red[0], s_red[1]), fmaxf(s_red[2], s_red[3]));
    float sc = 0.f;
    #pragma unroll
    for (int k = 0; k < PPT; ++k) {
        float w = __expf(mloc[k] - M);
        s_w[t + 256 * k] = w;
        sc += w * ms[2 * (t + 256 * k) + 1];
    }
    #pragma unroll
    for (int off = 32; off; off >>= 1) sc += __shfl_down(sc, off, 64);
    if (lane == 0) s_red[4 + wid] = sc;
    __syncthreads();
    float S = s_red[4] + s_red[5] + s_red[6] + s_red[7];
    int c = t & 15, g = t >> 4;
    int col4 = blockIdx.x * 16 + c;
    f4 a = (f4)0.f;
    #pragma unroll 8
    for (int i = 0; i < PPG; ++i) {
        int pp = g * PPG + i;
        a += s_w[pp] * ld4(ctxpart + (size_t)pp * D + 4 * col4);
    }
    s_acc[g][c] = a;
    __syncthreads();
    if (t < 16) {
        f4 aa = (f4)0.f;
        #pragma unroll
        for (int gg = 0; gg < 16; ++gg) aa += s_acc[gg][t];
        st4(aa * (1.f / S), ctx + 4 * (blockIdx.x * 16 + t));
    }
}

extern "C" void kernel_launch(void* const* d_in, const int* in_sizes, int n_in,
                              void* d_out, int out_size, void* d_ws, size_t ws_size,
                              hipStream_t stream) {
    const float* prev = (const float*)d_in[0];   // (8191, 4096)
    const float* inp  = (const float*)d_in[1];   // (4096,)
    const float* W_Q  = (const float*)d_in[2];
    const float* W_K  = (const float*)d_in[3];
    const float* W_V  = (const float*)d_in[4];
    float* out = (float*)d_out;                  // [0:4096]=output, [4096:]=inputs
    float* io  = out + D;
    float* ws  = (float*)d_ws;

    // ws: q D | kq D | ms 2*NWAVE | ctxpart NWAVE*D | ctx D   (~33.6 MB)
    float* q       = ws;
    float* kq      = q + D;
    float* ms      = kq + D;
    float* ctxpart = ms + 2 * NWAVE;
    float* ctx     = ctxpart + (size_t)NWAVE * D;

    // 1-2. projection chain (weight streams; run BEFORE copy so the weight
    //      traffic doesn't evict prev from L3 between copy and flash)
    k_matvec_rows<false><<<1024, 256, 0, stream>>>(W_Q, inp, nullptr, q);
    k_kq<<<256, 256, 0, stream>>>(W_K, q, kq);

    // 3. hand-rolled pure copy (ubench shape) — leaves prev L3-resident
    k_copy<<<2048, 256, 0, stream>>>(prev, inp, io);

    // 4. read-only flash on L3-hot prev
    k_flash_pure<<<512, 256, 0, stream>>>(prev, inp, kq, ms, ctxpart);

    // 5-6. combine + output projection
    k_combine<NWAVE><<<64, 256, 0, stream>>>(ms, ctxpart, ctx);
    k_matvec_rows<true><<<1024, 256, 0, stream>>>(W_V, ctx, inp, out);
}

// Round 15
// 133.897 us; speedup vs baseline: 1.0518x; 1.0518x over previous
//
#include <hip/hip_runtime.h>
#include <math.h>

#define D      4096
#define NPREV  8191
#define NROWS  8192
#define NWAVE  2048
#define RPW    4

typedef float f4 __attribute__((ext_vector_type(4)));

static __device__ __forceinline__ f4 nt_load4(const float* p) {
    return __builtin_nontemporal_load(reinterpret_cast<const f4*>(p));
}
static __device__ __forceinline__ f4 ld4(const float* p) {
    return *reinterpret_cast<const f4*>(p);
}
static __device__ __forceinline__ void st4(f4 v, float* p) {
    *reinterpret_cast<f4*>(p) = v;
}

// ---- copy role: blocks [0, cb) copy io f4 range [lo, hi) -------------------
static __device__ __forceinline__ void copy_slice(
        const float* __restrict__ prev, const float* __restrict__ inp,
        float* __restrict__ io, size_t lo, size_t hi, int cb) {
    const size_t stride = (size_t)cb * 256;
    for (size_t idx = lo + (size_t)blockIdx.x * 256 + threadIdx.x;
         idx < hi; idx += stride) {
        f4 v = (idx < (size_t)NPREV * (D / 4))
                 ? ld4(prev + 4 * idx)
                 : ld4(inp + 4 * (idx - (size_t)NPREV * (D / 4)));
        st4(v, io + 4 * idx);
    }
}

// ---- K1/K5: out[row] = dot(W[row,:], v) (+resid) + copy role ----------------
template<bool RESIDUAL>
__global__ void k_matvec_rows(const float* __restrict__ W, const float* __restrict__ v,
                              const float* __restrict__ resid, float* __restrict__ out,
                              const float* __restrict__ prev, const float* __restrict__ inp,
                              float* __restrict__ io, size_t lo, size_t hi, int cb) {
    if ((int)blockIdx.x < cb) { copy_slice(prev, inp, io, lo, hi, cb); return; }
    int row  = ((int)blockIdx.x - cb) * 4 + (threadIdx.x >> 6);
    int lane = threadIdx.x & 63;
    const float* Wrow = W + (size_t)row * D;
    float acc = 0.f;
    #pragma unroll
    for (int i = 0; i < 16; ++i) {
        int c = lane + i * 64;
        f4 w = nt_load4(Wrow + 4 * c);
        f4 x = ld4(v + 4 * c);
        acc += w.x * x.x + w.y * x.y + w.z * x.z + w.w * x.w;
    }
    #pragma unroll
    for (int off = 32; off; off >>= 1) acc += __shfl_down(acc, off, 64);
    if (lane == 0) out[row] = RESIDUAL ? (acc + resid[row]) : acc;
}

// ---- K2: kq[d] = sum_m q[m] * W_K[m][d] + copy role -------------------------
__global__ void k_kq(const float* __restrict__ W, const float* __restrict__ q,
                     float* __restrict__ kq,
                     const float* __restrict__ prev, const float* __restrict__ inp,
                     float* __restrict__ io, size_t lo, size_t hi, int cb) {
    if ((int)blockIdx.x < cb) { copy_slice(prev, inp, io, lo, hi, cb); return; }
    __shared__ float s_q[D];            // 16 KB
    __shared__ f4 s_part[64][4];        // 4 KB
    int t = threadIdx.x;
    int b = (int)blockIdx.x - cb;
    for (int i = t; i < D; i += 256) s_q[i] = q[i];
    __syncthreads();
    int c4 = b * 4 + (t & 3);           // f4 column
    int r0 = t >> 2;                    // 0..63
    f4 acc = (f4)0.f;
    #pragma unroll 16
    for (int i = 0; i < 64; ++i) {
        int m = r0 + i * 64;
        acc += s_q[m] * nt_load4(W + (size_t)m * D + 4 * c4);
    }
    s_part[r0][t & 3] = acc;
    __syncthreads();
    if (t < 4) {
        f4 a = (f4)0.f;
        #pragma unroll
        for (int g = 0; g < 64; ++g) a += s_part[g][t];
        st4(a, kq + 4 * (b * 4 + t));
    }
}

// ---- K3: read-only wave-autonomous flash + copy role ------------------------
__global__ __launch_bounds__(256, 2) void k_flash_pure(
        const float* __restrict__ prev, const float* __restrict__ inp,
        const float* __restrict__ kq,
        float* __restrict__ ms, float* __restrict__ ctxpart,
        float* __restrict__ io, size_t lo, size_t hi, int cb) {
    if ((int)blockIdx.x < cb) { copy_slice(prev, inp, io, lo, hi, cb); return; }
    const int t = threadIdx.x;
    const int lane = t & 63;
    const int gw = ((int)blockIdx.x - cb) * 4 + (t >> 6); // wave 0..2047

    f4 kqr[16];
    #pragma unroll
    for (int i = 0; i < 16; ++i) kqr[i] = ld4(kq + 4 * (lane + 64 * i));

    float m = -INFINITY, s = 0.f;
    f4 a[16];
    #pragma unroll
    for (int i = 0; i < 16; ++i) a[i] = (f4)0.f;

    for (int k = 0; k < RPW; ++k) {
        int n = gw + NWAVE * k;
        const float* src = (n < NPREV) ? (prev + (size_t)n * D) : inp;
        f4 x[16];
        #pragma unroll
        for (int i = 0; i < 16; ++i) x[i] = ld4(src + 4 * (lane + 64 * i));
        float p = 0.f;
        #pragma unroll
        for (int i = 0; i < 16; ++i)
            p += x[i].x * kqr[i].x + x[i].y * kqr[i].y
               + x[i].z * kqr[i].z + x[i].w * kqr[i].w;
        #pragma unroll
        for (int off = 32; off; off >>= 1) p += __shfl_down(p, off, 64);
        p = __shfl(p, 0, 64);                      // broadcast row logit
        if (p > m) {                               // wave-uniform rescale
            float sc = __expf(m - p);
            s *= sc;
            #pragma unroll
            for (int i = 0; i < 16; ++i) a[i] *= sc;
            m = p;
        }
        float e = __expf(p - m);
        s += e;
        #pragma unroll
        for (int i = 0; i < 16; ++i) a[i] += e * x[i];
    }
    float* cp = ctxpart + (size_t)gw * D;
    #pragma unroll
    for (int i = 0; i < 16; ++i) st4(a[i], cp + 4 * (lane + 64 * i));
    if (lane == 0) { ms[2 * gw] = m; ms[2 * gw + 1] = s; }
}

// ---- K4: combine NWAVE partials -> normalized ctx + copy role ---------------
template<int FBT>
__global__ void k_combine(const float* __restrict__ ms, const float* __restrict__ ctxpart,
                          float* __restrict__ ctx,
                          const float* __restrict__ prev, const float* __restrict__ inp,
                          float* __restrict__ io, size_t lo, size_t hi, int cb) {
    if ((int)blockIdx.x < cb) { copy_slice(prev, inp, io, lo, hi, cb); return; }
    constexpr int PPT = FBT / 256;      // ms pairs per thread
    constexpr int PPG = FBT / 16;       // partials per group-thread
    __shared__ float s_w[FBT];
    __shared__ float s_red[8];
    __shared__ f4 s_acc[16][16];
    int bb = (int)blockIdx.x - cb;      // 0..63
    int t = threadIdx.x;                // 256
    int lane = t & 63, wid = t >> 6;
    float mloc[PPT];
    float mx = -INFINITY;
    #pragma unroll
    for (int k = 0; k < PPT; ++k) { mloc[k] = ms[2 * (t + 256 * k)]; mx = fmaxf(mx, mloc[k]); }
    #pragma unroll
    for (int off = 32; off; off >>= 1) mx = fmaxf(mx, __shfl_down(mx, off, 64));
    if (lane == 0) s_red[wid] = mx;
    __syncthreads();
    float M = fmaxf(fmaxf(s_red[0], s_red[1]), fmaxf(s_red[2], s_red[3]));
    float sc = 0.f;
    #pragma unroll
    for (int k = 0; k < PPT; ++k) {
        float w = __expf(mloc[k] - M);
        s_w[t + 256 * k] = w;
        sc += w * ms[2 * (t + 256 * k) + 1];
    }
    #pragma unroll
    for (int off = 32; off; off >>= 1) sc += __shfl_down(sc, off, 64);
    if (lane == 0) s_red[4 + wid] = sc;
    __syncthreads();
    float S = s_red[4] + s_red[5] + s_red[6] + s_red[7];
    int c = t & 15, g = t >> 4;
    int col4 = bb * 16 + c;
    f4 a = (f4)0.f;
    #pragma unroll 8
    for (int i = 0; i < PPG; ++i) {
        int pp = g * PPG + i;
        a += s_w[pp] * ld4(ctxpart + (size_t)pp * D + 4 * col4);
    }
    s_acc[g][c] = a;
    __syncthreads();
    if (t < 16) {
        f4 aa = (f4)0.f;
        #pragma unroll
        for (int gg = 0; gg < 16; ++gg) aa += s_acc[gg][t];
        st4(aa * (1.f / S), ctx + 4 * (bb * 16 + t));
    }
}

extern "C" void kernel_launch(void* const* d_in, const int* in_sizes, int n_in,
                              void* d_out, int out_size, void* d_ws, size_t ws_size,
                              hipStream_t stream) {
    const float* prev = (const float*)d_in[0];   // (8191, 4096)
    const float* inp  = (const float*)d_in[1];   // (4096,)
    const float* W_Q  = (const float*)d_in[2];
    const float* W_K  = (const float*)d_in[3];
    const float* W_V  = (const float*)d_in[4];
    float* out = (float*)d_out;                  // [0:4096]=output, [4096:]=inputs
    float* io  = out + D;
    float* ws  = (float*)d_ws;

    // ws: q D | kq D | ms 2*NWAVE | ctxpart NWAVE*D | ctx D   (~33.6 MB)
    float* q       = ws;
    float* kq      = q + D;
    float* ms      = kq + D;
    float* ctxpart = ms + 2 * NWAVE;
    float* ctx     = ctxpart + (size_t)NWAVE * D;

    // io copy slice boundaries (f4 units; total 8192*1024 = 8,388,608)
    const size_t S0 = 0;
    const size_t S1 = 1572864;           // K1: 24 MB
    const size_t S2 = 3145728;           // K2: 24 MB
    const size_t S3 = 5242880;           // K3: 32 MB
    const size_t S4 = 5767168;           // K4: 8 MB
    const size_t S5 = 8388608;           // K5: 40 MB
    const int CB1 = 256, CB2 = 256, CB3 = 256, CB4 = 128, CB5 = 512;

    k_matvec_rows<false><<<CB1 + 1024, 256, 0, stream>>>(
        W_Q, inp, nullptr, q, prev, inp, io, S0, S1, CB1);
    k_kq<<<CB2 + 256, 256, 0, stream>>>(
        W_K, q, kq, prev, inp, io, S1, S2, CB2);
    k_flash_pure<<<CB3 + 512, 256, 0, stream>>>(
        prev, inp, kq, ms, ctxpart, io, S2, S3, CB3);
    k_combine<NWAVE><<<CB4 + 64, 256, 0, stream>>>(
        ms, ctxpart, ctx, prev, inp, io, S3, S4, CB4);
    k_matvec_rows<true><<<CB5 + 1024, 256, 0, stream>>>(
        W_V, ctx, inp, out, prev, inp, io, S4, S5, CB5);
}

// Round 16
// 124.422 us; speedup vs baseline: 1.1319x; 1.0761x over previous
//
#include <hip/hip_runtime.h>
#include <math.h>

#define D      4096
#define NPREV  8191
#define NROWS  8192
#define FB     512
#define FR     (NROWS / FB)   // 16

typedef float f4 __attribute__((ext_vector_type(4)));

static __device__ __forceinline__ f4 nt_load4(const float* p) {
    return __builtin_nontemporal_load(reinterpret_cast<const f4*>(p));
}
static __device__ __forceinline__ f4 ld4(const float* p) {
    return *reinterpret_cast<const f4*>(p);
}
static __device__ __forceinline__ void st4(f4 v, float* p) {
    *reinterpret_cast<f4*>(p) = v;
}

// ---- K1/K5: out[row] = dot(W[row,:], v) (+resid). 1024 blocks x 256 ---------
template<bool RESIDUAL>
__global__ void k_matvec_rows(const float* __restrict__ W, const float* __restrict__ v,
                              const float* __restrict__ resid, float* __restrict__ out) {
    int row  = blockIdx.x * 4 + (threadIdx.x >> 6);
    int lane = threadIdx.x & 63;
    const float* Wrow = W + (size_t)row * D;
    float acc = 0.f;
    #pragma unroll
    for (int i = 0; i < 16; ++i) {
        int c = lane + i * 64;
        f4 w = nt_load4(Wrow + 4 * c);
        f4 x = ld4(v + 4 * c);
        acc += w.x * x.x + w.y * x.y + w.z * x.z + w.w * x.w;
    }
    #pragma unroll
    for (int off = 32; off; off >>= 1) acc += __shfl_down(acc, off, 64);
    if (lane == 0) out[row] = RESIDUAL ? (acc + resid[row]) : acc;
}

// ---- K2: kq[d] = sum_m q[m] * W_K[m][d]. 256 blocks x 256 (R9-proven) -------
__global__ void k_kq(const float* __restrict__ W, const float* __restrict__ q,
                     float* __restrict__ kq) {
    __shared__ float s_q[D];            // 16 KB
    __shared__ f4 s_part[64][4];        // 4 KB
    int t = threadIdx.x;
    int b = blockIdx.x;
    for (int i = t; i < D; i += 256) s_q[i] = q[i];
    __syncthreads();
    int c4 = b * 4 + (t & 3);           // f4 column
    int r0 = t >> 2;                    // 0..63
    f4 acc = (f4)0.f;
    #pragma unroll 16
    for (int i = 0; i < 64; ++i) {
        int m = r0 + i * 64;
        acc += s_q[m] * nt_load4(W + (size_t)m * D + 4 * c4);
    }
    s_part[r0][t & 3] = acc;
    __syncthreads();
    if (t < 4) {
        f4 a = (f4)0.f;
        #pragma unroll
        for (int g = 0; g < 64; ++g) a += s_part[g][t];
        st4(a, kq + 4 * (b * 4 + t));
    }
}

// ---- K3: phased flash, verbatim R2/R3 structure (measured 75.2-75.9 us) -----
// FB=512 blocks x 1024 threads; wave-per-row copy+dot (phase A), LDS block
// softmax (phase B), column-wise re-read of prev (L2/L3-hot) for ctx partial
// (phase C). launch_bounds(1024,8) pins VGPR low (24-32 measured).
__global__ __launch_bounds__(1024, 8) void k_flash(
        const float* __restrict__ prev, const float* __restrict__ inp,
        const float* __restrict__ kq, float* __restrict__ io,
        float* __restrict__ ms, float* __restrict__ ctxpart) {
    __shared__ float s_log[FR];
    __shared__ float s_e[FR];
    const int n0 = blockIdx.x * FR;
    const int t = threadIdx.x;
    const int wid = t >> 6, lane = t & 63;

    // Phase A: each wave copies one row to io and dots it against kq
    {
        const int r = wid;               // 16 waves, 16 rows
        const int n = n0 + r;
        const float* src = (n < NPREV) ? (prev + (size_t)n * D) : inp;
        float* dst = io + (size_t)n * D;
        float acc = 0.f;
        #pragma unroll 4
        for (int i = lane; i < D / 4; i += 64) {
            f4 x = ld4(src + 4 * i);
            f4 k = ld4(kq + 4 * i);
            st4(x, dst + 4 * i);
            acc += x.x * k.x + x.y * k.y + x.z * k.z + x.w * k.w;
        }
        #pragma unroll
        for (int off = 32; off; off >>= 1) acc += __shfl_down(acc, off, 64);
        if (lane == 0) s_log[r] = acc;
    }
    __syncthreads();

    // Phase B: block-local softmax stats
    float m_b = -INFINITY;
    #pragma unroll
    for (int r = 0; r < FR; ++r) m_b = fmaxf(m_b, s_log[r]);
    if (t < FR) s_e[t] = __expf(s_log[t] - m_b);
    __syncthreads();
    float s_b = 0.f;
    #pragma unroll
    for (int r = 0; r < FR; ++r) s_b += s_e[r];

    // Phase C: ctx partial; thread t owns f4 column t; rows re-read from
    // prev/inp (L2/L3-hot after phase A)
    f4 a = (f4)0.f;
    #pragma unroll 4
    for (int r = 0; r < FR; ++r) {
        int n = n0 + r;
        const float* src = (n < NPREV) ? (prev + (size_t)n * D) : inp;
        a += s_e[r] * ld4(src + 4 * t);
    }
    st4(a, ctxpart + (size_t)blockIdx.x * D + 4 * t);
    if (t == 0) { ms[2 * blockIdx.x] = m_b; ms[2 * blockIdx.x + 1] = s_b; }
}

// ---- K4: combine FBT partials -> normalized ctx. 64 blocks x 256 ------------
template<int FBT>
__global__ void k_combine(const float* __restrict__ ms, const float* __restrict__ ctxpart,
                          float* __restrict__ ctx) {
    constexpr int PPT = FBT / 256;      // ms pairs per thread (2)
    constexpr int PPG = FBT / 16;       // partials per group-thread (32)
    __shared__ float s_w[FBT];
    __shared__ float s_red[8];
    __shared__ f4 s_acc[16][16];
    int t = threadIdx.x;                // 256
    int lane = t & 63, wid = t >> 6;
    float mloc[PPT];
    float mx = -INFINITY;
    #pragma unroll
    for (int k = 0; k < PPT; ++k) { mloc[k] = ms[2 * (t + 256 * k)]; mx = fmaxf(mx, mloc[k]); }
    #pragma unroll
    for (int off = 32; off; off >>= 1) mx = fmaxf(mx, __shfl_down(mx, off, 64));
    if (lane == 0) s_red[wid] = mx;
    __syncthreads();
    float M = fmaxf(fmaxf(s_red[0], s_red[1]), fmaxf(s_red[2], s_red[3]));
    float sc = 0.f;
    #pragma unroll
    for (int k = 0; k < PPT; ++k) {
        float w = __expf(mloc[k] - M);
        s_w[t + 256 * k] = w;
        sc += w * ms[2 * (t + 256 * k) + 1];
    }
    #pragma unroll
    for (int off = 32; off; off >>= 1) sc += __shfl_down(sc, off, 64);
    if (lane == 0) s_red[4 + wid] = sc;
    __syncthreads();
    float S = s_red[4] + s_red[5] + s_red[6] + s_red[7];
    int c = t & 15, g = t >> 4;
    int col4 = blockIdx.x * 16 + c;
    f4 a = (f4)0.f;
    #pragma unroll 8
    for (int i = 0; i < PPG; ++i) {
        int pp = g * PPG + i;
        a += s_w[pp] * ld4(ctxpart + (size_t)pp * D + 4 * col4);
    }
    s_acc[g][c] = a;
    __syncthreads();
    if (t < 16) {
        f4 aa = (f4)0.f;
        #pragma unroll
        for (int gg = 0; gg < 16; ++gg) aa += s_acc[gg][t];
        st4(aa * (1.f / S), ctx + 4 * (blockIdx.x * 16 + t));
    }
}

extern "C" void kernel_launch(void* const* d_in, const int* in_sizes, int n_in,
                              void* d_out, int out_size, void* d_ws, size_t ws_size,
                              hipStream_t stream) {
    const float* prev = (const float*)d_in[0];   // (8191, 4096)
    const float* inp  = (const float*)d_in[1];   // (4096,)
    const float* W_Q  = (const float*)d_in[2];
    const float* W_K  = (const float*)d_in[3];
    const float* W_V  = (const float*)d_in[4];
    float* out = (float*)d_out;                  // [0:4096]=output, [4096:]=inputs
    float* io  = out + D;
    float* ws  = (float*)d_ws;

    // ws: q D | kq D | ms 2*FB | ctxpart FB*D | ctx D   (~8.5 MB)
    float* q       = ws;
    float* kq      = q + D;
    float* ms      = kq + D;
    float* ctxpart = ms + 2 * FB;
    float* ctx     = ctxpart + (size_t)FB * D;

    k_matvec_rows<false><<<1024, 256, 0, stream>>>(W_Q, inp, nullptr, q);
    k_kq<<<256, 256, 0, stream>>>(W_K, q, kq);
    k_flash<<<FB, 1024, 0, stream>>>(prev, inp, kq, io, ms, ctxpart);
    k_combine<FB><<<64, 256, 0, stream>>>(ms, ctxpart, ctx);
    k_matvec_rows<true><<<1024, 256, 0, stream>>>(W_V, ctx, inp, out);
}